// Round 2
// baseline (482.017 us; speedup 1.0000x reference)
//
#include <hip/hip_runtime.h>
#include <stdint.h>

// TopKMS (OHEM top-k MSE): per-row MSE over [N, 512] fp32, mean of top-30% rows.
// R2: persistent grid-stride main kernel (R1 was workgroup-dispatch-rate bound:
// 16384 tiny workgroups, 950 GB/s, VALUBusy 5%). 2048 blocks, each wave loops
// over rows, 2 rows/iter for MLP. Histogram shrunk 16384->4096 bins (bin
// rel-width 2^-8, far inside 2% tolerance) to cut scan-kernel serial work.

#define D_FEAT 512
#define SCAN_THREADS 256
#define MAIN_BLOCKS 2048
#define MAIN_THREADS 256

__global__ __launch_bounds__(256) void zero_ws_kernel(int* __restrict__ ws, int n) {
    int i = blockIdx.x * blockDim.x + threadIdx.x;
    if (i < n) ws[i] = 0;
}

__global__ __launch_bounds__(MAIN_THREADS) void mse_hist_kernel(
    const float* __restrict__ input,
    const float* __restrict__ target,
    int n_rows,
    int* __restrict__ cnt_hist,
    float* __restrict__ sum_hist,
    int shift, int base, int nbins)
{
    const int lane   = threadIdx.x & 63;
    const int wave   = (blockIdx.x * MAIN_THREADS + threadIdx.x) >> 6;
    const int nwaves = (MAIN_BLOCKS * MAIN_THREADS) >> 6;   // 8192

    const float inv_d = 1.0f / (float)D_FEAT;

    // each wave handles 2 consecutive rows per iteration (8 float4 loads in
    // flight per lane -> 128 B/lane of MLP), grid-stride by 2*nwaves
    for (int row = wave * 2; row < n_rows; row += 2 * nwaves) {
        const float4* __restrict__ a0p = (const float4*)(input  + (size_t)row * D_FEAT);
        const float4* __restrict__ b0p = (const float4*)(target + (size_t)row * D_FEAT);

        float4 a00 = a0p[lane];
        float4 a01 = a0p[lane + 64];
        float4 b00 = b0p[lane];
        float4 b01 = b0p[lane + 64];

        const int row1 = row + 1;
        const bool has1 = (row1 < n_rows);
        const float4* __restrict__ a1p = (const float4*)(input  + (size_t)(has1 ? row1 : row) * D_FEAT);
        const float4* __restrict__ b1p = (const float4*)(target + (size_t)(has1 ? row1 : row) * D_FEAT);

        float4 a10 = a1p[lane];
        float4 a11 = a1p[lane + 64];
        float4 b10 = b1p[lane];
        float4 b11 = b1p[lane + 64];

        float acc0 = 0.0f, acc1 = 0.0f, d;
        d = a00.x - b00.x; acc0 += d * d;
        d = a00.y - b00.y; acc0 += d * d;
        d = a00.z - b00.z; acc0 += d * d;
        d = a00.w - b00.w; acc0 += d * d;
        d = a01.x - b01.x; acc0 += d * d;
        d = a01.y - b01.y; acc0 += d * d;
        d = a01.z - b01.z; acc0 += d * d;
        d = a01.w - b01.w; acc0 += d * d;

        d = a10.x - b10.x; acc1 += d * d;
        d = a10.y - b10.y; acc1 += d * d;
        d = a10.z - b10.z; acc1 += d * d;
        d = a10.w - b10.w; acc1 += d * d;
        d = a11.x - b11.x; acc1 += d * d;
        d = a11.y - b11.y; acc1 += d * d;
        d = a11.z - b11.z; acc1 += d * d;
        d = a11.w - b11.w; acc1 += d * d;

        // two independent wave-64 butterfly reductions
        #pragma unroll
        for (int off = 32; off > 0; off >>= 1) {
            acc0 += __shfl_xor(acc0, off, 64);
            acc1 += __shfl_xor(acc1, off, 64);
        }

        if (lane == 0) {
            float v0 = acc0 * inv_d;
            uint32_t bits0 = __float_as_uint(v0);
            int bin0 = (int)(bits0 >> shift) - base;
            bin0 = bin0 < 0 ? 0 : (bin0 > nbins - 1 ? nbins - 1 : bin0);
            atomicAdd(&cnt_hist[bin0], 1);
            atomicAdd(&sum_hist[bin0], v0);
            if (has1) {
                float v1 = acc1 * inv_d;
                uint32_t bits1 = __float_as_uint(v1);
                int bin1 = (int)(bits1 >> shift) - base;
                bin1 = bin1 < 0 ? 0 : (bin1 > nbins - 1 ? nbins - 1 : bin1);
                atomicAdd(&cnt_hist[bin1], 1);
                atomicAdd(&sum_hist[bin1], v1);
            }
        }
    }
}

__global__ __launch_bounds__(SCAN_THREADS) void topk_from_hist_kernel(
    const int* __restrict__ cnt_hist,
    const float* __restrict__ sum_hist,
    int nbins, int k,
    float* __restrict__ out)
{
    const int t = threadIdx.x;
    const int ch = nbins / SCAN_THREADS;     // bins per thread (16)
    const int start = nbins - 1 - t * ch;    // thread t owns a descending chunk

    int   c_t = 0;
    float s_t = 0.0f;
    for (int j = 0; j < ch; ++j) {
        int b = start - j;
        c_t += cnt_hist[b];
        s_t += sum_hist[b];
    }

    __shared__ int   cs[SCAN_THREADS];
    __shared__ float ss[SCAN_THREADS];
    cs[t] = c_t;
    ss[t] = s_t;
    __syncthreads();

    // Hillis-Steele inclusive scan over thread chunks (ordered top -> bottom)
    for (int off = 1; off < SCAN_THREADS; off <<= 1) {
        int cv = 0; float sv = 0.0f;
        if (t >= off) { cv = cs[t - off]; sv = ss[t - off]; }
        __syncthreads();
        cs[t] += cv;
        ss[t] += sv;
        __syncthreads();
    }

    const int   c_incl   = cs[t];
    const float s_incl   = ss[t];
    const int   c_before = c_incl - c_t;
    const float s_before = s_incl - s_t;

    // exactly one thread's chunk straddles rank k (total count == n_rows >= k)
    if (c_before < k && k <= c_incl) {
        int   cum = c_before;
        float s   = s_before;
        float result = 0.0f;
        for (int j = 0; j < ch; ++j) {
            int b = start - j;
            int c = cnt_hist[b];
            if (c == 0) continue;
            if (cum + c >= k) {
                int need = k - cum;
                float avg = sum_hist[b] / (float)c;   // bin mean: better than bin center
                result = (s + (float)need * avg) / (float)k;
                break;
            }
            cum += c;
            s   += sum_hist[b];
        }
        out[0] = result;
    }
}

extern "C" void kernel_launch(void* const* d_in, const int* in_sizes, int n_in,
                              void* d_out, int out_size, void* d_ws, size_t ws_size,
                              hipStream_t stream)
{
    const float* input  = (const float*)d_in[0];
    const float* target = (const float*)d_in[1];
    float* out = (float*)d_out;

    const int total  = in_sizes[0];
    const int n_rows = total / D_FEAT;            // 65536
    int k = (int)(0.3 * (double)n_rows);          // matches int(K_FRAC * n)
    if (k < 1) k = 1;
    if (k > n_rows) k = n_rows;

    // Histogram over float bit patterns, exponent range [2^-8, 2^8).
    // shift=15 -> 8 mantissa bits, 4096 bins (32 KB ws). Bin rel-width 2^-8,
    // and we use the bin mean, so error << the 2% tolerance.
    const int shift = (ws_size >= (size_t)(4096 * 8)) ? 15 : 17;
    const int mant_log2 = 23 - shift;
    const int nbins = 16 << mant_log2;
    const int base  = 119 << mant_log2;           // exponent field 119 == 2^-8

    int*   cnt_hist = (int*)d_ws;
    float* sum_hist = (float*)d_ws + nbins;

    const int zn = nbins * 2;                     // cnt + sum words (0 bits == 0.0f)
    zero_ws_kernel<<<(zn + 255) / 256, 256, 0, stream>>>((int*)d_ws, zn);

    mse_hist_kernel<<<MAIN_BLOCKS, MAIN_THREADS, 0, stream>>>(
        input, target, n_rows, cnt_hist, sum_hist, shift, base, nbins);

    topk_from_hist_kernel<<<1, SCAN_THREADS, 0, stream>>>(cnt_hist, sum_hist, nbins, k, out);
}

// Round 3
// 361.291 us; speedup vs baseline: 1.3342x; 1.3342x over previous
//
#include <hip/hip_runtime.h>
#include <hip/hip_fp16.h>
#include <stdint.h>

// TopKMS (OHEM top-k MSE): per-row MSE over [N, 512] fp32, mean of top-30% rows.
// R3: R1/R2 were limited by contended device-scope atomics to ~100 hot
// histogram bins (row-MSE ~ N(1, 0.0625) -> extreme bin concentration); R2's
// loop serialized on atomic completion via the vmcnt FIFO (VALUBusy 1.5%).
// Now: phase A streams inputs and stores per-row MSE (no atomics); phase B is
// a single-block LDS-histogram select (no global histogram, no zero kernel).

#define D_FEAT 512
#define NBINS 4096          // 256 bins/octave over [2^-8, 2^8)
#define HIST_SHIFT 15       // 8 mantissa bits
#define HIST_BASE (119 << 8)
#define SEL_THREADS 1024

// ---------------- Phase A: per-row MSE, one wave per 2 rows, no loop ----------
template <typename T>
__global__ __launch_bounds__(256) void mse_rows_kernel(
    const float* __restrict__ input,
    const float* __restrict__ target,
    int n_rows,
    T* __restrict__ rowmse)
{
    const int lane = threadIdx.x & 63;
    const int wave = threadIdx.x >> 6;
    const int row0 = (blockIdx.x * 4 + wave) * 2;
    if (row0 >= n_rows) return;
    const int row1 = row0 + 1;
    const bool has1 = (row1 < n_rows);

    const float4* __restrict__ a0 = (const float4*)(input  + (size_t)row0 * D_FEAT);
    const float4* __restrict__ b0 = (const float4*)(target + (size_t)row0 * D_FEAT);
    const float4* __restrict__ a1 = (const float4*)(input  + (size_t)(has1 ? row1 : row0) * D_FEAT);
    const float4* __restrict__ b1 = (const float4*)(target + (size_t)(has1 ? row1 : row0) * D_FEAT);

    // 8 float4 loads (128 B/lane) all issued before any waitcnt.
    float4 A00 = a0[lane], A01 = a0[lane + 64];
    float4 B00 = b0[lane], B01 = b0[lane + 64];
    float4 A10 = a1[lane], A11 = a1[lane + 64];
    float4 B10 = b1[lane], B11 = b1[lane + 64];

    float acc0 = 0.0f, acc1 = 0.0f, d;
    d = A00.x - B00.x; acc0 += d * d;
    d = A00.y - B00.y; acc0 += d * d;
    d = A00.z - B00.z; acc0 += d * d;
    d = A00.w - B00.w; acc0 += d * d;
    d = A01.x - B01.x; acc0 += d * d;
    d = A01.y - B01.y; acc0 += d * d;
    d = A01.z - B01.z; acc0 += d * d;
    d = A01.w - B01.w; acc0 += d * d;

    d = A10.x - B10.x; acc1 += d * d;
    d = A10.y - B10.y; acc1 += d * d;
    d = A10.z - B10.z; acc1 += d * d;
    d = A10.w - B10.w; acc1 += d * d;
    d = A11.x - B11.x; acc1 += d * d;
    d = A11.y - B11.y; acc1 += d * d;
    d = A11.z - B11.z; acc1 += d * d;
    d = A11.w - B11.w; acc1 += d * d;

    #pragma unroll
    for (int off = 32; off > 0; off >>= 1) {
        acc0 += __shfl_xor(acc0, off, 64);
        acc1 += __shfl_xor(acc1, off, 64);
    }

    if (lane == 0) {
        const float inv_d = 1.0f / (float)D_FEAT;
        rowmse[row0] = (T)(acc0 * inv_d);
        if (has1) rowmse[row1] = (T)(acc1 * inv_d);
    }
}

// ------------- Phase B: single-block LDS histogram + scan + result -----------
template <typename T>
__global__ __launch_bounds__(SEL_THREADS) void select_topk_kernel(
    const T* __restrict__ rowmse,
    int n_rows, int k,
    float* __restrict__ out)
{
    __shared__ int   cnt[NBINS];
    __shared__ float sum[NBINS];
    __shared__ int   cs[SEL_THREADS];
    __shared__ float ss[SEL_THREADS];

    const int t = threadIdx.x;

    for (int i = t; i < NBINS; i += SEL_THREADS) { cnt[i] = 0; sum[i] = 0.0f; }
    __syncthreads();

    for (int i = t; i < n_rows; i += SEL_THREADS) {
        float v = (float)rowmse[i];
        uint32_t bits = __float_as_uint(v);
        int bin = (int)(bits >> HIST_SHIFT) - HIST_BASE;
        bin = bin < 0 ? 0 : (bin > NBINS - 1 ? NBINS - 1 : bin);
        atomicAdd(&cnt[bin], 1);
        atomicAdd(&sum[bin], v);
    }
    __syncthreads();

    // descending chunks: thread t owns bins [start - ch + 1, start]
    const int ch = NBINS / SEL_THREADS;   // 4
    const int start = NBINS - 1 - t * ch;

    int   c_t = 0;
    float s_t = 0.0f;
    #pragma unroll
    for (int j = 0; j < ch; ++j) { c_t += cnt[start - j]; s_t += sum[start - j]; }
    cs[t] = c_t;
    ss[t] = s_t;
    __syncthreads();

    // Hillis-Steele inclusive scan (top -> bottom order)
    for (int off = 1; off < SEL_THREADS; off <<= 1) {
        int cv = 0; float sv = 0.0f;
        if (t >= off) { cv = cs[t - off]; sv = ss[t - off]; }
        __syncthreads();
        cs[t] += cv;
        ss[t] += sv;
        __syncthreads();
    }

    const int   c_incl   = cs[t];
    const float s_incl   = ss[t];
    const int   c_before = c_incl - c_t;
    const float s_before = s_incl - s_t;

    if (c_before < k && k <= c_incl) {
        int   cum = c_before;
        float s   = s_before;
        float result = 0.0f;
        for (int j = 0; j < ch; ++j) {
            int b = start - j;
            int c = cnt[b];
            if (c == 0) continue;
            if (cum + c >= k) {
                int need = k - cum;
                float avg = sum[b] / (float)c;   // bin mean, tighter than bin center
                result = (s + (float)need * avg) / (float)k;
                break;
            }
            cum += c;
            s   += sum[b];
        }
        out[0] = result;
    }
}

extern "C" void kernel_launch(void* const* d_in, const int* in_sizes, int n_in,
                              void* d_out, int out_size, void* d_ws, size_t ws_size,
                              hipStream_t stream)
{
    const float* input  = (const float*)d_in[0];
    const float* target = (const float*)d_in[1];
    float* out = (float*)d_out;

    const int total  = in_sizes[0];
    const int n_rows = total / D_FEAT;            // 65536
    int k = (int)(0.3 * (double)n_rows);          // matches int(K_FRAC * n)
    if (k < 1) k = 1;
    if (k > n_rows) k = n_rows;

    const int gridA = (n_rows + 7) / 8;           // 8 rows/block (4 waves x 2 rows)

    if (ws_size >= (size_t)n_rows * sizeof(float)) {
        float* rowmse = (float*)d_ws;
        mse_rows_kernel<float><<<gridA, 256, 0, stream>>>(input, target, n_rows, rowmse);
        select_topk_kernel<float><<<1, SEL_THREADS, 0, stream>>>(rowmse, n_rows, k, out);
    } else {
        // fp16 fallback (128 KB): rel. rounding ~5e-4, far inside 2% tolerance
        __half* rowmse = (__half*)d_ws;
        mse_rows_kernel<__half><<<gridA, 256, 0, stream>>>(input, target, n_rows, rowmse);
        select_topk_kernel<__half><<<1, SEL_THREADS, 0, stream>>>(rowmse, n_rows, k, out);
    }
}

// Round 4
// 294.391 us; speedup vs baseline: 1.6373x; 1.2273x over previous
//
#include <hip/hip_runtime.h>
#include <stdint.h>

// TopKMS (OHEM top-k MSE): per-row MSE over [N, 512] fp32, mean of top-30% rows.
// R4: R1/R3's phase A was workgroup-dispatch-rate bound (~21-28 cyc/wg at the
// CP; 8-16K tiny blocks). Now 1024 persistent-ish blocks (4/CU, all resident),
// each wave unrolls 4 rows x 4 iters (16 float4 loads in flight). No atomics
// anywhere in the streaming path (R2 showed global atomics in a loop serialize
// on the vmcnt FIFO). Select = 16-block LDS-hist partials (non-atomic global
// writes) + single-block merge/scan.

#define D_FEAT 512
#define NBINS 4096          // 256 bins/octave over [2^-8, 2^8)
#define HIST_SHIFT 15       // 8 mantissa bits
#define HIST_BASE (119 << 8)
#define NPARTS 16
#define SEL_THREADS 1024
#define ROWS_PER_WAVE 16
#define ROWS_PER_BLOCK 64   // 4 waves/block

// ---------------- Phase A: per-row MSE, 16 rows/wave, no atomics -------------
__global__ __launch_bounds__(256) void mse_rows_kernel(
    const float* __restrict__ input,
    const float* __restrict__ target,
    int n_rows,
    float* __restrict__ rowmse)
{
    const int lane = threadIdx.x & 63;
    const int wave = threadIdx.x >> 6;
    const int wave_base = blockIdx.x * ROWS_PER_BLOCK + wave * ROWS_PER_WAVE;
    if (wave_base >= n_rows) return;
    const float inv_d = 1.0f / (float)D_FEAT;

    #pragma unroll
    for (int it = 0; it < 4; ++it) {
        const int row = wave_base + it * 4;

        float4 A[4][2], B[4][2];
        #pragma unroll
        for (int j = 0; j < 4; ++j) {
            int r = row + j;
            if (r >= n_rows) r = n_rows - 1;          // clamp (tail safety)
            const float4* __restrict__ a = (const float4*)(input  + (size_t)r * D_FEAT);
            const float4* __restrict__ b = (const float4*)(target + (size_t)r * D_FEAT);
            A[j][0] = a[lane];
            A[j][1] = a[lane + 64];
            B[j][0] = b[lane];
            B[j][1] = b[lane + 64];
        }

        float acc[4];
        #pragma unroll
        for (int j = 0; j < 4; ++j) {
            float s = 0.0f, d;
            d = A[j][0].x - B[j][0].x; s += d * d;
            d = A[j][0].y - B[j][0].y; s += d * d;
            d = A[j][0].z - B[j][0].z; s += d * d;
            d = A[j][0].w - B[j][0].w; s += d * d;
            d = A[j][1].x - B[j][1].x; s += d * d;
            d = A[j][1].y - B[j][1].y; s += d * d;
            d = A[j][1].z - B[j][1].z; s += d * d;
            d = A[j][1].w - B[j][1].w; s += d * d;
            acc[j] = s;
        }

        #pragma unroll
        for (int off = 32; off > 0; off >>= 1) {
            #pragma unroll
            for (int j = 0; j < 4; ++j)
                acc[j] += __shfl_xor(acc[j], off, 64);
        }

        if (lane == 0) {
            if (row + 3 < n_rows) {
                float4 v = make_float4(acc[0] * inv_d, acc[1] * inv_d,
                                       acc[2] * inv_d, acc[3] * inv_d);
                *(float4*)(rowmse + row) = v;
            } else {
                #pragma unroll
                for (int j = 0; j < 4; ++j)
                    if (row + j < n_rows) rowmse[row + j] = acc[j] * inv_d;
            }
        }
    }
}

// ------- Phase B1: per-slice LDS histogram, non-atomic global partials -------
__global__ __launch_bounds__(SEL_THREADS) void hist_part_kernel(
    const float* __restrict__ rowmse,
    int n_rows,
    int* __restrict__ part_cnt,     // [NPARTS][NBINS]
    float* __restrict__ part_sum)   // [NPARTS][NBINS]
{
    __shared__ int   cnt[NBINS];
    __shared__ float sum[NBINS];
    const int t = threadIdx.x;

    for (int i = t; i < NBINS; i += SEL_THREADS) { cnt[i] = 0; sum[i] = 0.0f; }
    __syncthreads();

    const int chunk = (n_rows + NPARTS - 1) / NPARTS;
    const int lo = blockIdx.x * chunk;
    const int hi = min(n_rows, lo + chunk);

    for (int i = lo + t; i < hi; i += SEL_THREADS) {
        float v = rowmse[i];
        uint32_t bits = __float_as_uint(v);
        int bin = (int)(bits >> HIST_SHIFT) - HIST_BASE;
        bin = bin < 0 ? 0 : (bin > NBINS - 1 ? NBINS - 1 : bin);
        atomicAdd(&cnt[bin], 1);      // LDS-scope, low contention (~100/bin max)
        atomicAdd(&sum[bin], v);
    }
    __syncthreads();

    int*   pc = part_cnt + (size_t)blockIdx.x * NBINS;
    float* ps = part_sum + (size_t)blockIdx.x * NBINS;
    for (int i = t; i < NBINS; i += SEL_THREADS) { pc[i] = cnt[i]; ps[i] = sum[i]; }
}

// --------- Phase B2: single-block merge of partials + scan + result ----------
__global__ __launch_bounds__(SEL_THREADS) void merge_scan_kernel(
    const int* __restrict__ part_cnt,
    const float* __restrict__ part_sum,
    int k,
    float* __restrict__ out)
{
    __shared__ int   cnt[NBINS];
    __shared__ float sum[NBINS];
    __shared__ int   cs[SEL_THREADS];
    __shared__ float ss[SEL_THREADS];
    const int t = threadIdx.x;

    for (int i = t; i < NBINS; i += SEL_THREADS) {
        int   c = 0;
        float s = 0.0f;
        #pragma unroll
        for (int b = 0; b < NPARTS; ++b) {
            c += part_cnt[(size_t)b * NBINS + i];
            s += part_sum[(size_t)b * NBINS + i];
        }
        cnt[i] = c;
        sum[i] = s;
    }
    __syncthreads();

    // descending chunks: thread t owns bins [start - ch + 1, start]
    const int ch = NBINS / SEL_THREADS;   // 4
    const int start = NBINS - 1 - t * ch;

    int   c_t = 0;
    float s_t = 0.0f;
    #pragma unroll
    for (int j = 0; j < ch; ++j) { c_t += cnt[start - j]; s_t += sum[start - j]; }
    cs[t] = c_t;
    ss[t] = s_t;
    __syncthreads();

    // Hillis-Steele inclusive scan (top -> bottom order)
    for (int off = 1; off < SEL_THREADS; off <<= 1) {
        int cv = 0; float sv = 0.0f;
        if (t >= off) { cv = cs[t - off]; sv = ss[t - off]; }
        __syncthreads();
        cs[t] += cv;
        ss[t] += sv;
        __syncthreads();
    }

    const int   c_incl   = cs[t];
    const float s_incl   = ss[t];
    const int   c_before = c_incl - c_t;
    const float s_before = s_incl - s_t;

    if (c_before < k && k <= c_incl) {
        int   cum = c_before;
        float s   = s_before;
        float result = 0.0f;
        for (int j = 0; j < ch; ++j) {
            int b = start - j;
            int c = cnt[b];
            if (c == 0) continue;
            if (cum + c >= k) {
                int need = k - cum;
                float avg = sum[b] / (float)c;   // bin mean, tighter than bin center
                result = (s + (float)need * avg) / (float)k;
                break;
            }
            cum += c;
            s   += sum[b];
        }
        out[0] = result;
    }
}

// ---- Fallback single-block select (only used if d_ws is tiny) ---------------
__global__ __launch_bounds__(SEL_THREADS) void select_topk_kernel(
    const float* __restrict__ rowmse,
    int n_rows, int k,
    float* __restrict__ out)
{
    __shared__ int   cnt[NBINS];
    __shared__ float sum[NBINS];
    __shared__ int   cs[SEL_THREADS];
    __shared__ float ss[SEL_THREADS];
    const int t = threadIdx.x;

    for (int i = t; i < NBINS; i += SEL_THREADS) { cnt[i] = 0; sum[i] = 0.0f; }
    __syncthreads();
    for (int i = t; i < n_rows; i += SEL_THREADS) {
        float v = rowmse[i];
        uint32_t bits = __float_as_uint(v);
        int bin = (int)(bits >> HIST_SHIFT) - HIST_BASE;
        bin = bin < 0 ? 0 : (bin > NBINS - 1 ? NBINS - 1 : bin);
        atomicAdd(&cnt[bin], 1);
        atomicAdd(&sum[bin], v);
    }
    __syncthreads();

    const int ch = NBINS / SEL_THREADS;
    const int start = NBINS - 1 - t * ch;
    int c_t = 0; float s_t = 0.0f;
    #pragma unroll
    for (int j = 0; j < ch; ++j) { c_t += cnt[start - j]; s_t += sum[start - j]; }
    cs[t] = c_t; ss[t] = s_t;
    __syncthreads();
    for (int off = 1; off < SEL_THREADS; off <<= 1) {
        int cv = 0; float sv = 0.0f;
        if (t >= off) { cv = cs[t - off]; sv = ss[t - off]; }
        __syncthreads();
        cs[t] += cv; ss[t] += sv;
        __syncthreads();
    }
    const int c_incl = cs[t], c_before = c_incl - c_t;
    const float s_before = ss[t] - s_t;
    if (c_before < k && k <= c_incl) {
        int cum = c_before; float s = s_before; float result = 0.0f;
        for (int j = 0; j < ch; ++j) {
            int b = start - j;
            int c = cnt[b];
            if (c == 0) continue;
            if (cum + c >= k) {
                int need = k - cum;
                result = (s + (float)need * (sum[b] / (float)c)) / (float)k;
                break;
            }
            cum += c; s += sum[b];
        }
        out[0] = result;
    }
}

extern "C" void kernel_launch(void* const* d_in, const int* in_sizes, int n_in,
                              void* d_out, int out_size, void* d_ws, size_t ws_size,
                              hipStream_t stream)
{
    const float* input  = (const float*)d_in[0];
    const float* target = (const float*)d_in[1];
    float* out = (float*)d_out;

    const int total  = in_sizes[0];
    const int n_rows = total / D_FEAT;            // 65536
    int k = (int)(0.3 * (double)n_rows);          // matches int(K_FRAC * n)
    if (k < 1) k = 1;
    if (k > n_rows) k = n_rows;

    const int gridA = (n_rows + ROWS_PER_BLOCK - 1) / ROWS_PER_BLOCK;   // 1024

    const size_t rowmse_bytes = (size_t)n_rows * sizeof(float);
    const size_t part_bytes   = (size_t)NPARTS * NBINS * (sizeof(int) + sizeof(float));

    float* rowmse = (float*)d_ws;
    mse_rows_kernel<<<gridA, 256, 0, stream>>>(input, target, n_rows, rowmse);

    if (ws_size >= rowmse_bytes + part_bytes) {
        int*   part_cnt = (int*)((char*)d_ws + rowmse_bytes);
        float* part_sum = (float*)((char*)d_ws + rowmse_bytes + (size_t)NPARTS * NBINS * sizeof(int));
        hist_part_kernel<<<NPARTS, SEL_THREADS, 0, stream>>>(rowmse, n_rows, part_cnt, part_sum);
        merge_scan_kernel<<<1, SEL_THREADS, 0, stream>>>(part_cnt, part_sum, k, out);
    } else {
        select_topk_kernel<<<1, SEL_THREADS, 0, stream>>>(rowmse, n_rows, k, out);
    }
}

// Round 6
// 261.843 us; speedup vs baseline: 1.8409x; 1.1243x over previous
//
#include <hip/hip_runtime.h>
#include <stdint.h>

// TopKMS (OHEM top-k MSE): per-row MSE over [N, 512] fp32, mean of top-30% rows.
// R6 = R5 with compile fix: __builtin_nontemporal_load needs a clang-native
// vector type, not HIP_vector_type. Theory unchanged: phase A pinned at
// ~2.5 TB/s across R1/R3/R4 with all pipes idle; suspects are cache thrash
// (inputs ~= L3 size, restored every replay) + insufficient occupancy/MLP.
// Fix: 2048 blocks (8/CU -> 32 waves/CU), grid-stride 2 rows/wave/iter,
// nontemporal loads to stream past the caches.

#define D_FEAT 512
#define NBINS 4096          // 256 bins/octave over [2^-8, 2^8)
#define HIST_SHIFT 15       // 8 mantissa bits
#define HIST_BASE (119 << 8)
#define NPARTS 16
#define SEL_THREADS 1024
#define MAIN_BLOCKS 2048
#define MAIN_THREADS 256

typedef float f32x4 __attribute__((ext_vector_type(4)));

// ---------------- Phase A: per-row MSE, grid-stride, NT loads ----------------
__global__ __launch_bounds__(MAIN_THREADS) void mse_rows_kernel(
    const float* __restrict__ input,
    const float* __restrict__ target,
    int n_rows,
    float* __restrict__ rowmse)
{
    const int lane   = threadIdx.x & 63;
    const int wave   = (blockIdx.x * MAIN_THREADS + threadIdx.x) >> 6;
    const int nwaves = (MAIN_BLOCKS * MAIN_THREADS) >> 6;   // 8192
    const float inv_d = 1.0f / (float)D_FEAT;

    for (int row = wave * 2; row < n_rows; row += 2 * nwaves) {
        const int row1 = row + 1;
        const bool has1 = (row1 < n_rows);

        const f32x4* __restrict__ a0 = (const f32x4*)(input  + (size_t)row * D_FEAT);
        const f32x4* __restrict__ b0 = (const f32x4*)(target + (size_t)row * D_FEAT);
        const f32x4* __restrict__ a1 = (const f32x4*)(input  + (size_t)(has1 ? row1 : row) * D_FEAT);
        const f32x4* __restrict__ b1 = (const f32x4*)(target + (size_t)(has1 ? row1 : row) * D_FEAT);

        f32x4 A00 = __builtin_nontemporal_load(&a0[lane]);
        f32x4 A01 = __builtin_nontemporal_load(&a0[lane + 64]);
        f32x4 B00 = __builtin_nontemporal_load(&b0[lane]);
        f32x4 B01 = __builtin_nontemporal_load(&b0[lane + 64]);
        f32x4 A10 = __builtin_nontemporal_load(&a1[lane]);
        f32x4 A11 = __builtin_nontemporal_load(&a1[lane + 64]);
        f32x4 B10 = __builtin_nontemporal_load(&b1[lane]);
        f32x4 B11 = __builtin_nontemporal_load(&b1[lane + 64]);

        f32x4 d0 = A00 - B00;
        f32x4 d1 = A01 - B01;
        f32x4 d2 = A10 - B10;
        f32x4 d3 = A11 - B11;

        float acc0 = d0.x * d0.x + d0.y * d0.y + d0.z * d0.z + d0.w * d0.w
                   + d1.x * d1.x + d1.y * d1.y + d1.z * d1.z + d1.w * d1.w;
        float acc1 = d2.x * d2.x + d2.y * d2.y + d2.z * d2.z + d2.w * d2.w
                   + d3.x * d3.x + d3.y * d3.y + d3.z * d3.z + d3.w * d3.w;

        #pragma unroll
        for (int off = 32; off > 0; off >>= 1) {
            acc0 += __shfl_xor(acc0, off, 64);
            acc1 += __shfl_xor(acc1, off, 64);
        }

        if (lane == 0) {
            rowmse[row] = acc0 * inv_d;
            if (has1) rowmse[row1] = acc1 * inv_d;
        }
    }
}

// ------- Phase B1: per-slice LDS histogram, non-atomic global partials -------
__global__ __launch_bounds__(SEL_THREADS) void hist_part_kernel(
    const float* __restrict__ rowmse,
    int n_rows,
    int* __restrict__ part_cnt,     // [NPARTS][NBINS]
    float* __restrict__ part_sum)   // [NPARTS][NBINS]
{
    __shared__ int   cnt[NBINS];
    __shared__ float sum[NBINS];
    const int t = threadIdx.x;

    for (int i = t; i < NBINS; i += SEL_THREADS) { cnt[i] = 0; sum[i] = 0.0f; }
    __syncthreads();

    const int chunk = (n_rows + NPARTS - 1) / NPARTS;
    const int lo = blockIdx.x * chunk;
    const int hi = min(n_rows, lo + chunk);

    for (int i = lo + t; i < hi; i += SEL_THREADS) {
        float v = rowmse[i];
        uint32_t bits = __float_as_uint(v);
        int bin = (int)(bits >> HIST_SHIFT) - HIST_BASE;
        bin = bin < 0 ? 0 : (bin > NBINS - 1 ? NBINS - 1 : bin);
        atomicAdd(&cnt[bin], 1);      // LDS-scope, low contention per slice
        atomicAdd(&sum[bin], v);
    }
    __syncthreads();

    int*   pc = part_cnt + (size_t)blockIdx.x * NBINS;
    float* ps = part_sum + (size_t)blockIdx.x * NBINS;
    for (int i = t; i < NBINS; i += SEL_THREADS) { pc[i] = cnt[i]; ps[i] = sum[i]; }
}

// --------- Phase B2: single-block merge of partials + scan + result ----------
__global__ __launch_bounds__(SEL_THREADS) void merge_scan_kernel(
    const int* __restrict__ part_cnt,
    const float* __restrict__ part_sum,
    int k,
    float* __restrict__ out)
{
    __shared__ int   cnt[NBINS];
    __shared__ float sum[NBINS];
    __shared__ int   cs[SEL_THREADS];
    __shared__ float ss[SEL_THREADS];
    const int t = threadIdx.x;

    for (int i = t; i < NBINS; i += SEL_THREADS) {
        int   c = 0;
        float s = 0.0f;
        #pragma unroll
        for (int b = 0; b < NPARTS; ++b) {
            c += part_cnt[(size_t)b * NBINS + i];
            s += part_sum[(size_t)b * NBINS + i];
        }
        cnt[i] = c;
        sum[i] = s;
    }
    __syncthreads();

    // descending chunks: thread t owns bins [start - ch + 1, start]
    const int ch = NBINS / SEL_THREADS;   // 4
    const int start = NBINS - 1 - t * ch;

    int   c_t = 0;
    float s_t = 0.0f;
    #pragma unroll
    for (int j = 0; j < ch; ++j) { c_t += cnt[start - j]; s_t += sum[start - j]; }
    cs[t] = c_t;
    ss[t] = s_t;
    __syncthreads();

    // Hillis-Steele inclusive scan (top -> bottom order)
    for (int off = 1; off < SEL_THREADS; off <<= 1) {
        int cv = 0; float sv = 0.0f;
        if (t >= off) { cv = cs[t - off]; sv = ss[t - off]; }
        __syncthreads();
        cs[t] += cv;
        ss[t] += sv;
        __syncthreads();
    }

    const int   c_incl   = cs[t];
    const float s_incl   = ss[t];
    const int   c_before = c_incl - c_t;
    const float s_before = s_incl - s_t;

    if (c_before < k && k <= c_incl) {
        int   cum = c_before;
        float s   = s_before;
        float result = 0.0f;
        for (int j = 0; j < ch; ++j) {
            int b = start - j;
            int c = cnt[b];
            if (c == 0) continue;
            if (cum + c >= k) {
                int need = k - cum;
                float avg = sum[b] / (float)c;   // bin mean, tighter than bin center
                result = (s + (float)need * avg) / (float)k;
                break;
            }
            cum += c;
            s   += sum[b];
        }
        out[0] = result;
    }
}

// ---- Fallback single-block select (only used if d_ws is tiny) ---------------
__global__ __launch_bounds__(SEL_THREADS) void select_topk_kernel(
    const float* __restrict__ rowmse,
    int n_rows, int k,
    float* __restrict__ out)
{
    __shared__ int   cnt[NBINS];
    __shared__ float sum[NBINS];
    __shared__ int   cs[SEL_THREADS];
    __shared__ float ss[SEL_THREADS];
    const int t = threadIdx.x;

    for (int i = t; i < NBINS; i += SEL_THREADS) { cnt[i] = 0; sum[i] = 0.0f; }
    __syncthreads();
    for (int i = t; i < n_rows; i += SEL_THREADS) {
        float v = rowmse[i];
        uint32_t bits = __float_as_uint(v);
        int bin = (int)(bits >> HIST_SHIFT) - HIST_BASE;
        bin = bin < 0 ? 0 : (bin > NBINS - 1 ? NBINS - 1 : bin);
        atomicAdd(&cnt[bin], 1);
        atomicAdd(&sum[bin], v);
    }
    __syncthreads();

    const int ch = NBINS / SEL_THREADS;
    const int start = NBINS - 1 - t * ch;
    int c_t = 0; float s_t = 0.0f;
    #pragma unroll
    for (int j = 0; j < ch; ++j) { c_t += cnt[start - j]; s_t += sum[start - j]; }
    cs[t] = c_t; ss[t] = s_t;
    __syncthreads();
    for (int off = 1; off < SEL_THREADS; off <<= 1) {
        int cv = 0; float sv = 0.0f;
        if (t >= off) { cv = cs[t - off]; sv = ss[t - off]; }
        __syncthreads();
        cs[t] += cv; ss[t] += sv;
        __syncthreads();
    }
    const int c_incl = cs[t], c_before = c_incl - c_t;
    const float s_before = ss[t] - s_t;
    if (c_before < k && k <= c_incl) {
        int cum = c_before; float s = s_before; float result = 0.0f;
        for (int j = 0; j < ch; ++j) {
            int b = start - j;
            int c = cnt[b];
            if (c == 0) continue;
            if (cum + c >= k) {
                int need = k - cum;
                result = (s + (float)need * (sum[b] / (float)c)) / (float)k;
                break;
            }
            cum += c; s += sum[b];
        }
        out[0] = result;
    }
}

extern "C" void kernel_launch(void* const* d_in, const int* in_sizes, int n_in,
                              void* d_out, int out_size, void* d_ws, size_t ws_size,
                              hipStream_t stream)
{
    const float* input  = (const float*)d_in[0];
    const float* target = (const float*)d_in[1];
    float* out = (float*)d_out;

    const int total  = in_sizes[0];
    const int n_rows = total / D_FEAT;            // 65536
    int k = (int)(0.3 * (double)n_rows);          // matches int(K_FRAC * n)
    if (k < 1) k = 1;
    if (k > n_rows) k = n_rows;

    const size_t rowmse_bytes = (size_t)n_rows * sizeof(float);
    const size_t part_bytes   = (size_t)NPARTS * NBINS * (sizeof(int) + sizeof(float));

    float* rowmse = (float*)d_ws;
    mse_rows_kernel<<<MAIN_BLOCKS, MAIN_THREADS, 0, stream>>>(input, target, n_rows, rowmse);

    if (ws_size >= rowmse_bytes + part_bytes) {
        int*   part_cnt = (int*)((char*)d_ws + rowmse_bytes);
        float* part_sum = (float*)((char*)d_ws + rowmse_bytes + (size_t)NPARTS * NBINS * sizeof(int));
        hist_part_kernel<<<NPARTS, SEL_THREADS, 0, stream>>>(rowmse, n_rows, part_cnt, part_sum);
        merge_scan_kernel<<<1, SEL_THREADS, 0, stream>>>(part_cnt, part_sum, k, out);
    } else {
        select_topk_kernel<<<1, SEL_THREADS, 0, stream>>>(rowmse, n_rows, k, out);
    }
}